// Round 2
// baseline (9757.506 us; speedup 1.0000x reference)
//
#include <hip/hip_runtime.h>
#include <hip/hip_bf16.h>
#include <hip/hip_cooperative_groups.h>
#include <stdint.h>

namespace cg = cooperative_groups;

#define HIDDEN 1024
#define FEAT   64
#define BATCH  512
#define SEQ    64
#define GATES  3072        // 3*HIDDEN
#define CHUNK_T 16         // timesteps per gates_x chunk

typedef __attribute__((ext_vector_type(4))) float f32x4;
typedef __attribute__((ext_vector_type(8))) short s16x8;   // 8 bf16 = 4 VGPRs (MFMA A/B frag)

__device__ inline unsigned short f2bf(float f) {
    unsigned u = __builtin_bit_cast(unsigned, f);
    u += 0x7fff + ((u >> 16) & 1);          // round-to-nearest-even (finite inputs)
    return (unsigned short)(u >> 16);
}
__device__ inline float bf2f(unsigned short s) {
    unsigned u = ((unsigned)s) << 16;
    return __builtin_bit_cast(float, u);
}

#define GLOAD_LDS16(g, l) __builtin_amdgcn_global_load_lds( \
    (const __attribute__((address_space(1))) unsigned int*)(g), \
    (__attribute__((address_space(3))) unsigned int*)(l), 16, 0, 0)

// ---------------- weight/input conversion ----------------
__global__ void k_convert(const float* __restrict__ src, unsigned short* __restrict__ dst, int n) {
    int i = blockIdx.x * blockDim.x + threadIdx.x;
    if (i < n) dst[i] = f2bf(src[i]);
}

// Whh (3*H, H) fp32 -> WhhR bf16 with rows permuted so unit-tile ub's 48 rows
// {r:16, z:16, n:16} are contiguous: dst row d = ub*48 + g*16 + jj <- src row g*1024 + ub*16 + jj
__global__ void k_conv_whh(const float* __restrict__ src, unsigned short* __restrict__ dst) {
    int i = blockIdx.x * 256 + threadIdx.x;          // 3072*1024 threads
    int d = i >> 10, k = i & 1023;
    int ub = d / 48, rem = d - ub * 48;
    int g = rem >> 4, jj = rem & 15;
    int srow = g * 1024 + ub * 16 + jj;
    dst[i] = f2bf(src[(size_t)srow * 1024 + k]);
}

// x (B,T,F) fp32 -> xbf (T,B,F) bf16  (t-major so a chunk of timesteps is GEMM-row-contiguous)
__global__ void k_xpose(const float* __restrict__ x, unsigned short* __restrict__ xbf) {
    int i = blockIdx.x * blockDim.x + threadIdx.x;
    if (i >= BATCH * SEQ * FEAT) return;
    int f = i & 63, t = (i >> 6) & 63, b = i >> 12;
    xbf[((size_t)t * BATCH + b) * FEAT + f] = f2bf(x[i]);
}

// ---------------- BT-form MFMA GEMM for gates_x ----------------
template<int BM, int BN, int BK, bool STORE_BF16>
__global__ __launch_bounds__(256) void k_gemm_bt(
    const unsigned short* __restrict__ A,
    const unsigned short* __restrict__ B,
    const float* __restrict__ bias,
    void* __restrict__ C,
    int K, int ldc)
{
    __shared__ unsigned short As[BM * BK];
    __shared__ unsigned short Bs[BN * BK];
    const int tileN = blockIdx.x * BN;
    const int tileM = blockIdx.y * BM;
    const int wid  = threadIdx.x >> 6;
    const int lane = threadIdx.x & 63;
    constexpr int WM = BM / 2, WN = BN / 2;
    constexpr int FM = WM / 16, FN = WN / 16;
    const int wm0 = (wid >> 1) * WM;
    const int wn0 = (wid & 1) * WN;

    f32x4 acc[FM][FN];
    const f32x4 zero = {0.f, 0.f, 0.f, 0.f};
#pragma unroll
    for (int i = 0; i < FM; ++i)
#pragma unroll
        for (int j = 0; j < FN; ++j) acc[i][j] = zero;

    constexpr int SPR = BK / 8;
    constexpr int RA = BM * SPR / 256;
    constexpr int RB = BN * SPR / 256;

    for (int k0 = 0; k0 < K; k0 += BK) {
        __syncthreads();
#pragma unroll
        for (int r = 0; r < RA; ++r) {
            int sbase = r * 256 + wid * 64;
            int s = sbase + lane;
            int row = s >> 3, cs = s & (SPR - 1);
            const unsigned short* g = A + (size_t)(tileM + row) * K + k0 + cs * 8;
            GLOAD_LDS16(g, As + sbase * 8);
        }
#pragma unroll
        for (int r = 0; r < RB; ++r) {
            int sbase = r * 256 + wid * 64;
            int s = sbase + lane;
            int row = s >> 3, cs = s & (SPR - 1);
            const unsigned short* g = B + (size_t)(tileN + row) * K + k0 + cs * 8;
            GLOAD_LDS16(g, Bs + sbase * 8);
        }
        __syncthreads();

#pragma unroll
        for (int kk = 0; kk < BK / 32; ++kk) {
            s16x8 a[FM], b[FN];
#pragma unroll
            for (int i = 0; i < FM; ++i)
                a[i] = *(const s16x8*)&As[(wm0 + i * 16 + (lane & 15)) * BK + kk * 32 + (lane >> 4) * 8];
#pragma unroll
            for (int j = 0; j < FN; ++j)
                b[j] = *(const s16x8*)&Bs[(wn0 + j * 16 + (lane & 15)) * BK + kk * 32 + (lane >> 4) * 8];
#pragma unroll
            for (int i = 0; i < FM; ++i)
#pragma unroll
                for (int j = 0; j < FN; ++j)
                    acc[i][j] = __builtin_amdgcn_mfma_f32_16x16x32_bf16(a[i], b[j], acc[i][j], 0, 0, 0);
        }
    }

    const int r4 = (lane >> 4) * 4;
    const int cn = lane & 15;
#pragma unroll
    for (int i = 0; i < FM; ++i)
#pragma unroll
        for (int j = 0; j < FN; ++j)
#pragma unroll
            for (int r = 0; r < 4; ++r) {
                int row = tileM + wm0 + i * 16 + r4 + r;
                int col = tileN + wn0 + j * 16 + cn;
                float v = acc[i][j][r];
                if (bias) v += bias[col];
                if (STORE_BF16)
                    ((unsigned short*)C)[(size_t)row * ldc + col] = f2bf(v);
                else
                    ((float*)C)[(size_t)row * ldc + col] = v;
            }
}

// ---------------- persistent fused recurrent kernel (one chunk = 16 timesteps) ----------------
// grid = 256 blocks x 256 threads (1 block/CU). Block (mb,ub): rows [mb*128, +128), units [ub*16, +16).
// WhhR slab (48 x 1024 bf16) LDS-resident for the whole chunk (16B row pad -> conflict-free b128 reads).
// A (h_{t-1} bf16 from hseq) read global->VGPR directly. Gates fused in epilogue; h carried fp32 in hf.
__global__ __launch_bounds__(256) void k_gru_fused(
    const unsigned short* __restrict__ gx,     // (CHUNK_T*BATCH, 3072) bf16
    unsigned short* __restrict__ hseq,         // (SEQ, BATCH, HIDDEN) bf16: reads t-1, writes t
    const unsigned short* __restrict__ whhR,   // (3072, 1024) bf16, rows permuted per k_conv_whh
    const float* __restrict__ bhh,
    float* __restrict__ hf,                    // (BATCH, HIDDEN) fp32 carry
    int t0)
{
    __shared__ unsigned short Bs[48 * 1032];   // 16-bf16 row pad: stride 2064 B -> <=2-way banks
    const int bid = blockIdx.x;
    const int mb = bid >> 6;
    const int ub = bid & 63;
    const int tid = threadIdx.x;
    const int wid = tid >> 6, lane = tid & 63;
    const int l15 = lane & 15, hi = lane >> 4;

    // ---- stage the 48x1024 Whh slab once (wave-uniform half-row segments keep dest linear+padded) ----
    {
        const unsigned short* slab = whhR + (size_t)ub * 48 * 1024;
#pragma unroll
        for (int r = 0; r < 24; ++r) {
            int sbase = r * 256 + wid * 64;                 // wave-uniform; 64-seg = half a 128-seg row
            int row = sbase >> 7;
            int dstbase = row * 1032 + (sbase & 127) * 8;   // element offset, wave-uniform
            GLOAD_LDS16(slab + (size_t)(sbase + lane) * 8, Bs + dstbase);
        }
    }
    __syncthreads();

    const int wm0 = wid * 32;                        // wave owns 32 rows (FM=2)
    const int row0 = mb * 128 + wm0 + l15;           // a-frag M-row (i=0); +16 for i=1
    const int erow0 = mb * 128 + wm0 + hi * 4;       // epilogue row base: + i*16 + r
    const int j = ub * 16 + l15;                     // unit index (C/D col = lane&15)
    const float bh_r = bhh[j], bh_z = bhh[HIDDEN + j], bh_n = bhh[2 * HIDDEN + j];

    cg::grid_group grid = cg::this_grid();

    for (int tt = 0; tt < CHUNK_T; ++tt) {
        const int t = t0 + tt;
        f32x4 acc[2][3];
        const f32x4 zero = {0.f, 0.f, 0.f, 0.f};
#pragma unroll
        for (int i = 0; i < 2; ++i)
#pragma unroll
            for (int g = 0; g < 3; ++g) acc[i][g] = zero;

        if (t > 0) {
            const unsigned short* hp = hseq + (size_t)(t - 1) * (BATCH * HIDDEN);
            const unsigned short* pa0 = hp + (size_t)row0 * HIDDEN + hi * 8;
            const unsigned short* pa1 = pa0 + 16 * HIDDEN;
#pragma unroll 4
            for (int ks = 0; ks < 32; ++ks) {                 // K = 1024 in 32-wide slices
                s16x8 a0 = *(const s16x8*)(pa0 + ks * 32);
                s16x8 a1 = *(const s16x8*)(pa1 + ks * 32);
                s16x8 b0 = *(const s16x8*)&Bs[(l15) * 1032 + ks * 32 + hi * 8];
                s16x8 b1 = *(const s16x8*)&Bs[(16 + l15) * 1032 + ks * 32 + hi * 8];
                s16x8 b2 = *(const s16x8*)&Bs[(32 + l15) * 1032 + ks * 32 + hi * 8];
                acc[0][0] = __builtin_amdgcn_mfma_f32_16x16x32_bf16(a0, b0, acc[0][0], 0, 0, 0);
                acc[0][1] = __builtin_amdgcn_mfma_f32_16x16x32_bf16(a0, b1, acc[0][1], 0, 0, 0);
                acc[0][2] = __builtin_amdgcn_mfma_f32_16x16x32_bf16(a0, b2, acc[0][2], 0, 0, 0);
                acc[1][0] = __builtin_amdgcn_mfma_f32_16x16x32_bf16(a1, b0, acc[1][0], 0, 0, 0);
                acc[1][1] = __builtin_amdgcn_mfma_f32_16x16x32_bf16(a1, b1, acc[1][1], 0, 0, 0);
                acc[1][2] = __builtin_amdgcn_mfma_f32_16x16x32_bf16(a1, b2, acc[1][2], 0, 0, 0);
            }
        }

        // ---- fused gate epilogue: acc[.][0]=r-gate, [1]=z, [2]=n partials ----
#pragma unroll
        for (int i = 0; i < 2; ++i)
#pragma unroll
            for (int r = 0; r < 4; ++r) {
                int brow = erow0 + i * 16 + r;
                size_t gxi = ((size_t)(tt * BATCH + brow)) * GATES + j;
                float xr = bf2f(gx[gxi]);
                float xz = bf2f(gx[gxi + HIDDEN]);
                float xn = bf2f(gx[gxi + 2 * HIDDEN]);
                float rg = 1.f / (1.f + __expf(-(xr + acc[i][0][r] + bh_r)));
                float zg = 1.f / (1.f + __expf(-(xz + acc[i][1][r] + bh_z)));
                float ng = tanhf(xn + rg * (acc[i][2][r] + bh_n));
                size_t hidx = (size_t)brow * HIDDEN + j;
                float hv = hf[hidx];
                float hnew = (1.f - zg) * ng + zg * hv;
                hf[hidx] = hnew;
                hseq[(size_t)t * (BATCH * HIDDEN) + hidx] = f2bf(hnew);
            }

        grid.sync();   // h_t visible to all blocks before step t+1
    }
}

// ---------------- batch-norm over batch: fold to per-unit affine ----------------
__global__ void k_bn_stats(const float* __restrict__ h, const float* __restrict__ gamma,
                           const float* __restrict__ beta, float* __restrict__ a, float* __restrict__ bb)
{
    int j = blockIdx.x * 256 + threadIdx.x;
    float s = 0.f, q = 0.f;
    for (int b = 0; b < BATCH; ++b) {
        float v = h[(size_t)b * HIDDEN + j];
        s += v; q += v * v;
    }
    float mu = s * (1.f / BATCH);
    float var = q * (1.f / BATCH) - mu * mu;
    float rs = rsqrtf(var + 1e-5f);
    float aj = gamma[j] * rs;
    a[j] = aj;
    bb[j] = beta[j] - mu * aj;
}

// ---------------- FC(1024->1) + sigmoid ----------------
__global__ void k_fc(const float* __restrict__ h, const float* __restrict__ a, const float* __restrict__ bb,
                     const float* __restrict__ fcW, const float* __restrict__ fcb, float* __restrict__ out)
{
    int b = blockIdx.x;
    int lane = threadIdx.x;
    float s = 0.f;
    for (int j = lane; j < HIDDEN; j += 64)
        s += (h[(size_t)b * HIDDEN + j] * a[j] + bb[j]) * fcW[j];
#pragma unroll
    for (int m = 32; m; m >>= 1) s += __shfl_xor(s, m, 64);
    if (lane == 0) out[b] = 1.f / (1.f + __expf(-(s + fcb[0])));
}

// ---------------- driver ----------------
extern "C" void kernel_launch(void* const* d_in, const int* in_sizes, int n_in,
                              void* d_out, int out_size, void* d_ws, size_t ws_size,
                              hipStream_t stream)
{
    const float* x = (const float*)d_in[0];
    const float* W_ih[3] = {(const float*)d_in[1], (const float*)d_in[5], (const float*)d_in[9]};
    const float* W_hh[3] = {(const float*)d_in[2], (const float*)d_in[6], (const float*)d_in[10]};
    const float* b_ih[3] = {(const float*)d_in[3], (const float*)d_in[7], (const float*)d_in[11]};
    const float* b_hh[3] = {(const float*)d_in[4], (const float*)d_in[8], (const float*)d_in[12]};
    const float* gamma = (const float*)d_in[13];
    const float* beta  = (const float*)d_in[14];
    const float* fcW   = (const float*)d_in[15];
    const float* fcb   = (const float*)d_in[16];

    char* ws = (char*)d_ws;
    size_t off = 0;
    auto alloc = [&](size_t bytes) -> void* {
        void* p = ws + off;
        off = (off + bytes + 255) & ~(size_t)255;
        return p;
    };
    unsigned short* wih[3]; unsigned short* whhR[3];
    wih[0]  = (unsigned short*)alloc((size_t)GATES * FEAT * 2);
    whhR[0] = (unsigned short*)alloc((size_t)GATES * HIDDEN * 2);
    wih[1]  = (unsigned short*)alloc((size_t)GATES * HIDDEN * 2);
    whhR[1] = (unsigned short*)alloc((size_t)GATES * HIDDEN * 2);
    wih[2]  = (unsigned short*)alloc((size_t)GATES * HIDDEN * 2);
    whhR[2] = (unsigned short*)alloc((size_t)GATES * HIDDEN * 2);
    unsigned short* xbf   = (unsigned short*)alloc((size_t)SEQ * BATCH * FEAT * 2);
    unsigned short* hseqA = (unsigned short*)alloc((size_t)SEQ * BATCH * HIDDEN * 2);
    unsigned short* hseqB = (unsigned short*)alloc((size_t)SEQ * BATCH * HIDDEN * 2);
    unsigned short* gx    = (unsigned short*)alloc((size_t)CHUNK_T * BATCH * GATES * 2);
    float* hf   = (float*)alloc((size_t)BATCH * HIDDEN * 4);
    float* abuf = (float*)alloc(HIDDEN * 4);
    float* bbuf = (float*)alloc(HIDDEN * 4);

    // weights -> bf16 (stateless every call)
    k_convert<<<(GATES * FEAT + 255) / 256, 256, 0, stream>>>(W_ih[0], wih[0], GATES * FEAT);
    for (int L = 0; L < 3; ++L) {
        k_conv_whh<<<(GATES * HIDDEN) / 256, 256, 0, stream>>>(W_hh[L], whhR[L]);
        if (L) k_convert<<<(GATES * HIDDEN + 255) / 256, 256, 0, stream>>>(W_ih[L], wih[L], GATES * HIDDEN);
    }
    k_xpose<<<(BATCH * SEQ * FEAT + 255) / 256, 256, 0, stream>>>(x, xbf);

    const unsigned short* inseq = xbf;
    unsigned short* outseq = hseqA;
    for (int L = 0; L < 3; ++L) {
        int Kin = (L == 0) ? FEAT : HIDDEN;
        hipMemsetAsync(hf, 0, (size_t)BATCH * HIDDEN * 4, stream);   // h0 = 0
        for (int c = 0; c < SEQ / CHUNK_T; ++c) {
            dim3 g1(GATES / 128, (CHUNK_T * BATCH) / 128);
            k_gemm_bt<128, 128, 64, true><<<g1, 256, 0, stream>>>(
                inseq + (size_t)c * CHUNK_T * BATCH * Kin, wih[L], b_ih[L], gx, Kin, GATES);

            const unsigned short* gxp = gx;
            unsigned short* outp = outseq;
            const unsigned short* whhp = whhR[L];
            const float* bhhp = b_hh[L];
            float* hfp = hf;
            int t0 = c * CHUNK_T;
            void* args[] = {(void*)&gxp, (void*)&outp, (void*)&whhp, (void*)&bhhp, (void*)&hfp, (void*)&t0};
            hipLaunchCooperativeKernel((const void*)k_gru_fused, dim3(256), dim3(256), args, 0, stream);
        }
        inseq = outseq;
        outseq = (outseq == hseqA) ? hseqB : hseqA;
    }

    k_bn_stats<<<HIDDEN / 256, 256, 0, stream>>>(hf, gamma, beta, abuf, bbuf);
    k_fc<<<BATCH, 64, 0, stream>>>(hf, abuf, bbuf, fcW, fcb, (float*)d_out);
}

// Round 3
// 4650.691 us; speedup vs baseline: 2.0981x; 2.0981x over previous
//
#include <hip/hip_runtime.h>
#include <hip/hip_bf16.h>
#include <stdint.h>

#define HIDDEN 1024
#define FEAT   64
#define BATCH  512
#define SEQ    64
#define GATES  3072        // 3*HIDDEN
#define CHUNK_T 16         // timesteps per gates_x chunk

typedef __attribute__((ext_vector_type(4))) float f32x4;
typedef __attribute__((ext_vector_type(8))) short s16x8;   // 8 bf16 = 4 VGPRs (MFMA A/B frag)

__device__ inline unsigned short f2bf(float f) {
    unsigned u = __builtin_bit_cast(unsigned, f);
    u += 0x7fff + ((u >> 16) & 1);          // round-to-nearest-even (finite inputs)
    return (unsigned short)(u >> 16);
}
__device__ inline float bf2f(unsigned short s) {
    unsigned u = ((unsigned)s) << 16;
    return __builtin_bit_cast(float, u);
}

#define GLOAD_LDS16(g, l) __builtin_amdgcn_global_load_lds( \
    (const __attribute__((address_space(1))) unsigned int*)(g), \
    (__attribute__((address_space(3))) unsigned int*)(l), 16, 0, 0)

// ---------------- weight/input conversion ----------------
__global__ void k_convert(const float* __restrict__ src, unsigned short* __restrict__ dst, int n) {
    int i = blockIdx.x * blockDim.x + threadIdx.x;
    if (i < n) dst[i] = f2bf(src[i]);
}

// Whh (3*H, H) fp32 -> WhhR bf16, rows permuted so unit-tile ub's 48 rows
// {r:16, z:16, n:16} are contiguous: dst row d = ub*48 + g*16 + jj <- src row g*1024 + ub*16 + jj
__global__ void k_conv_whh(const float* __restrict__ src, unsigned short* __restrict__ dst) {
    int i = blockIdx.x * 256 + threadIdx.x;          // 3072*1024 threads
    int d = i >> 10, k = i & 1023;
    int ub = d / 48, rem = d - ub * 48;
    int g = rem >> 4, jj = rem & 15;
    int srow = g * 1024 + ub * 16 + jj;
    dst[i] = f2bf(src[(size_t)srow * 1024 + k]);
}

// x (B,T,F) fp32 -> xbf (T,B,F) bf16
__global__ void k_xpose(const float* __restrict__ x, unsigned short* __restrict__ xbf) {
    int i = blockIdx.x * blockDim.x + threadIdx.x;
    if (i >= BATCH * SEQ * FEAT) return;
    int f = i & 63, t = (i >> 6) & 63, b = i >> 12;
    xbf[((size_t)t * BATCH + b) * FEAT + f] = f2bf(x[i]);
}

// ---------------- BT-form MFMA GEMM for gates_x (round-1 proven) ----------------
template<int BM, int BN, int BK, bool STORE_BF16>
__global__ __launch_bounds__(256) void k_gemm_bt(
    const unsigned short* __restrict__ A,
    const unsigned short* __restrict__ B,
    const float* __restrict__ bias,
    void* __restrict__ C,
    int K, int ldc)
{
    __shared__ unsigned short As[BM * BK];
    __shared__ unsigned short Bs[BN * BK];
    const int tileN = blockIdx.x * BN;
    const int tileM = blockIdx.y * BM;
    const int wid  = threadIdx.x >> 6;
    const int lane = threadIdx.x & 63;
    constexpr int WM = BM / 2, WN = BN / 2;
    constexpr int FM = WM / 16, FN = WN / 16;
    const int wm0 = (wid >> 1) * WM;
    const int wn0 = (wid & 1) * WN;

    f32x4 acc[FM][FN];
    const f32x4 zero = {0.f, 0.f, 0.f, 0.f};
#pragma unroll
    for (int i = 0; i < FM; ++i)
#pragma unroll
        for (int j = 0; j < FN; ++j) acc[i][j] = zero;

    constexpr int SPR = BK / 8;
    constexpr int RA = BM * SPR / 256;
    constexpr int RB = BN * SPR / 256;

    for (int k0 = 0; k0 < K; k0 += BK) {
        __syncthreads();
#pragma unroll
        for (int r = 0; r < RA; ++r) {
            int sbase = r * 256 + wid * 64;
            int s = sbase + lane;
            int row = s >> 3, cs = s & (SPR - 1);
            const unsigned short* g = A + (size_t)(tileM + row) * K + k0 + cs * 8;
            GLOAD_LDS16(g, As + sbase * 8);
        }
#pragma unroll
        for (int r = 0; r < RB; ++r) {
            int sbase = r * 256 + wid * 64;
            int s = sbase + lane;
            int row = s >> 3, cs = s & (SPR - 1);
            const unsigned short* g = B + (size_t)(tileN + row) * K + k0 + cs * 8;
            GLOAD_LDS16(g, Bs + sbase * 8);
        }
        __syncthreads();

#pragma unroll
        for (int kk = 0; kk < BK / 32; ++kk) {
            s16x8 a[FM], b[FN];
#pragma unroll
            for (int i = 0; i < FM; ++i)
                a[i] = *(const s16x8*)&As[(wm0 + i * 16 + (lane & 15)) * BK + kk * 32 + (lane >> 4) * 8];
#pragma unroll
            for (int j = 0; j < FN; ++j)
                b[j] = *(const s16x8*)&Bs[(wn0 + j * 16 + (lane & 15)) * BK + kk * 32 + (lane >> 4) * 8];
#pragma unroll
            for (int i = 0; i < FM; ++i)
#pragma unroll
                for (int j = 0; j < FN; ++j)
                    acc[i][j] = __builtin_amdgcn_mfma_f32_16x16x32_bf16(a[i], b[j], acc[i][j], 0, 0, 0);
        }
    }

    const int r4 = (lane >> 4) * 4;
    const int cn = lane & 15;
#pragma unroll
    for (int i = 0; i < FM; ++i)
#pragma unroll
        for (int j = 0; j < FN; ++j)
#pragma unroll
            for (int r = 0; r < 4; ++r) {
                int row = tileM + wm0 + i * 16 + r4 + r;
                int col = tileN + wn0 + j * 16 + cn;
                float v = acc[i][j][r];
                if (bias) v += bias[col];
                if (STORE_BF16)
                    ((unsigned short*)C)[(size_t)row * ldc + col] = f2bf(v);
                else
                    ((float*)C)[(size_t)row * ldc + col] = v;
            }
}

// ---------------- fused per-timestep recurrent kernel ----------------
// grid 256 x 256 threads. mb = blockIdx&3 (XCD-affine under %8 round-robin), ub = blockIdx>>2.
// Block: rows [mb*128,+128) x units [ub*16,+16), all 3 gates.
// B = 48 permuted Whh rows staged once into LDS (XOR-swizzled, conflict-free b128 reads);
// A (h_{t-1}) read directly global->VGPR. Zero barriers in the K-loop. Gate math in epilogue.
__global__ __launch_bounds__(256) void k_step(
    const unsigned short* __restrict__ gx,     // (CHUNK_T*BATCH, 3072) bf16
    unsigned short* __restrict__ hseq,         // (SEQ, BATCH, HIDDEN) bf16
    const unsigned short* __restrict__ whhR,   // (3072, 1024) bf16 permuted
    const float* __restrict__ bhh,
    float* __restrict__ hf,                    // (BATCH, HIDDEN) fp32 carry
    int t, int gxrow0)                         // absolute t; tt*BATCH
{
    __shared__ unsigned short Bs[48 * 1024];   // 96 KB, XOR-swizzled content
    const int bid = blockIdx.x;
    const int mb = bid & 3;
    const int ub = bid >> 2;
    const int tid = threadIdx.x;
    const int wid = tid >> 6, lane = tid & 63;
    const int l15 = lane & 15, hi = lane >> 4;

    const int wm0 = wid * 32;                  // wave owns 32 rows (FM=2)
    const int j = ub * 16 + l15;               // unit index (C/D col = lane&15)

    f32x4 acc[2][3];
    const f32x4 zero = {0.f, 0.f, 0.f, 0.f};
#pragma unroll
    for (int i = 0; i < 2; ++i)
#pragma unroll
        for (int g = 0; g < 3; ++g) acc[i][g] = zero;

    if (t > 0) {
        // ---- stage B slab (48x1024 bf16 = 96 groups of 1024B), pre-swizzled source ----
        {
            const char* slab = (const char*)(whhR + (size_t)ub * 48 * 1024);
            char* lbase = (char*)Bs;
            int laneoff = lane << 4;
#pragma unroll
            for (int r = 0; r < 24; ++r) {
                int group = wid * 24 + r;
                int base = group << 10;                 // byte offset in slab
                int s = ((base >> 11) & 7) << 4;        // row = base>>11, wave-uniform
                GLOAD_LDS16(slab + base + (laneoff ^ s), lbase + base);
            }
        }
        __syncthreads();

        // ---- K-loop: 32 slices of K=32; A direct from global, B from swizzled LDS ----
        const char* aBase = (const char*)(hseq + (size_t)(t - 1) * (BATCH * HIDDEN));
        const char* pa0 = aBase + (size_t)(mb * 128 + wm0 + l15) * 2048 + (hi << 4);
        const char* pa1 = pa0 + 16 * 2048;
        const char* lB = (const char*)Bs;
        const int swz = (l15 & 7) << 4;
        const int boff0 = (l15)      * 2048 + (hi << 4);
        const int boff1 = (16 + l15) * 2048 + (hi << 4);
        const int boff2 = (32 + l15) * 2048 + (hi << 4);
#pragma unroll 4
        for (int ks = 0; ks < 32; ++ks) {
            s16x8 a0 = *(const s16x8*)(pa0 + ks * 64);
            s16x8 a1 = *(const s16x8*)(pa1 + ks * 64);
            s16x8 b0 = *(const s16x8*)(lB + ((boff0 + ks * 64) ^ swz));
            s16x8 b1 = *(const s16x8*)(lB + ((boff1 + ks * 64) ^ swz));
            s16x8 b2 = *(const s16x8*)(lB + ((boff2 + ks * 64) ^ swz));
            acc[0][0] = __builtin_amdgcn_mfma_f32_16x16x32_bf16(a0, b0, acc[0][0], 0, 0, 0);
            acc[0][1] = __builtin_amdgcn_mfma_f32_16x16x32_bf16(a0, b1, acc[0][1], 0, 0, 0);
            acc[0][2] = __builtin_amdgcn_mfma_f32_16x16x32_bf16(a0, b2, acc[0][2], 0, 0, 0);
            acc[1][0] = __builtin_amdgcn_mfma_f32_16x16x32_bf16(a1, b0, acc[1][0], 0, 0, 0);
            acc[1][1] = __builtin_amdgcn_mfma_f32_16x16x32_bf16(a1, b1, acc[1][1], 0, 0, 0);
            acc[1][2] = __builtin_amdgcn_mfma_f32_16x16x32_bf16(a1, b2, acc[1][2], 0, 0, 0);
        }
    }

    // ---- fused gate epilogue: acc[.][0]=r, [1]=z, [2]=n partials ----
    const float bh_r = bhh[j], bh_z = bhh[HIDDEN + j], bh_n = bhh[2 * HIDDEN + j];
    const int erow0 = mb * 128 + wm0 + hi * 4;
#pragma unroll
    for (int i = 0; i < 2; ++i)
#pragma unroll
        for (int r = 0; r < 4; ++r) {
            int brow = erow0 + i * 16 + r;
            size_t gxi = ((size_t)(gxrow0 + brow)) * GATES + j;
            float xr = bf2f(gx[gxi]);
            float xz = bf2f(gx[gxi + HIDDEN]);
            float xn = bf2f(gx[gxi + 2 * HIDDEN]);
            float rg = 1.f / (1.f + __expf(-(xr + acc[i][0][r] + bh_r)));
            float zg = 1.f / (1.f + __expf(-(xz + acc[i][1][r] + bh_z)));
            float ng = tanhf(xn + rg * (acc[i][2][r] + bh_n));
            size_t hidx = (size_t)brow * HIDDEN + j;
            float hv = (t > 0) ? hf[hidx] : 0.f;
            float hnew = (1.f - zg) * ng + zg * hv;
            hf[hidx] = hnew;
            hseq[(size_t)t * (BATCH * HIDDEN) + hidx] = f2bf(hnew);
        }
}

// ---------------- batch-norm over batch: fold to per-unit affine ----------------
__global__ void k_bn_stats(const float* __restrict__ h, const float* __restrict__ gamma,
                           const float* __restrict__ beta, float* __restrict__ a, float* __restrict__ bb)
{
    int j = blockIdx.x * 256 + threadIdx.x;
    float s = 0.f, q = 0.f;
    for (int b = 0; b < BATCH; ++b) {
        float v = h[(size_t)b * HIDDEN + j];
        s += v; q += v * v;
    }
    float mu = s * (1.f / BATCH);
    float var = q * (1.f / BATCH) - mu * mu;
    float rs = rsqrtf(var + 1e-5f);
    float aj = gamma[j] * rs;
    a[j] = aj;
    bb[j] = beta[j] - mu * aj;
}

// ---------------- FC(1024->1) + sigmoid ----------------
__global__ void k_fc(const float* __restrict__ h, const float* __restrict__ a, const float* __restrict__ bb,
                     const float* __restrict__ fcW, const float* __restrict__ fcb, float* __restrict__ out)
{
    int b = blockIdx.x;
    int lane = threadIdx.x;
    float s = 0.f;
    for (int j = lane; j < HIDDEN; j += 64)
        s += (h[(size_t)b * HIDDEN + j] * a[j] + bb[j]) * fcW[j];
#pragma unroll
    for (int m = 32; m; m >>= 1) s += __shfl_xor(s, m, 64);
    if (lane == 0) out[b] = 1.f / (1.f + __expf(-(s + fcb[0])));
}

// ---------------- driver ----------------
extern "C" void kernel_launch(void* const* d_in, const int* in_sizes, int n_in,
                              void* d_out, int out_size, void* d_ws, size_t ws_size,
                              hipStream_t stream)
{
    const float* x = (const float*)d_in[0];
    const float* W_ih[3] = {(const float*)d_in[1], (const float*)d_in[5], (const float*)d_in[9]};
    const float* W_hh[3] = {(const float*)d_in[2], (const float*)d_in[6], (const float*)d_in[10]};
    const float* b_ih[3] = {(const float*)d_in[3], (const float*)d_in[7], (const float*)d_in[11]};
    const float* b_hh[3] = {(const float*)d_in[4], (const float*)d_in[8], (const float*)d_in[12]};
    const float* gamma = (const float*)d_in[13];
    const float* beta  = (const float*)d_in[14];
    const float* fcW   = (const float*)d_in[15];
    const float* fcb   = (const float*)d_in[16];

    char* ws = (char*)d_ws;
    size_t off = 0;
    auto alloc = [&](size_t bytes) -> void* {
        void* p = ws + off;
        off = (off + bytes + 255) & ~(size_t)255;
        return p;
    };
    unsigned short* wih[3]; unsigned short* whhR[3];
    wih[0]  = (unsigned short*)alloc((size_t)GATES * FEAT * 2);
    whhR[0] = (unsigned short*)alloc((size_t)GATES * HIDDEN * 2);
    wih[1]  = (unsigned short*)alloc((size_t)GATES * HIDDEN * 2);
    whhR[1] = (unsigned short*)alloc((size_t)GATES * HIDDEN * 2);
    wih[2]  = (unsigned short*)alloc((size_t)GATES * HIDDEN * 2);
    whhR[2] = (unsigned short*)alloc((size_t)GATES * HIDDEN * 2);
    unsigned short* xbf   = (unsigned short*)alloc((size_t)SEQ * BATCH * FEAT * 2);
    unsigned short* hseqA = (unsigned short*)alloc((size_t)SEQ * BATCH * HIDDEN * 2);
    unsigned short* hseqB = (unsigned short*)alloc((size_t)SEQ * BATCH * HIDDEN * 2);
    unsigned short* gx    = (unsigned short*)alloc((size_t)CHUNK_T * BATCH * GATES * 2);
    float* hf   = (float*)alloc((size_t)BATCH * HIDDEN * 4);
    float* abuf = (float*)alloc(HIDDEN * 4);
    float* bbuf = (float*)alloc(HIDDEN * 4);

    // weights -> bf16 (stateless every call)
    k_convert<<<(GATES * FEAT + 255) / 256, 256, 0, stream>>>(W_ih[0], wih[0], GATES * FEAT);
    for (int L = 0; L < 3; ++L) {
        k_conv_whh<<<(GATES * HIDDEN) / 256, 256, 0, stream>>>(W_hh[L], whhR[L]);
        if (L) k_convert<<<(GATES * HIDDEN + 255) / 256, 256, 0, stream>>>(W_ih[L], wih[L], GATES * HIDDEN);
    }
    k_xpose<<<(BATCH * SEQ * FEAT + 255) / 256, 256, 0, stream>>>(x, xbf);

    const unsigned short* inseq = xbf;
    unsigned short* outseq = hseqA;
    for (int L = 0; L < 3; ++L) {
        int Kin = (L == 0) ? FEAT : HIDDEN;
        for (int c = 0; c < SEQ / CHUNK_T; ++c) {
            dim3 g1(GATES / 128, (CHUNK_T * BATCH) / 128);
            k_gemm_bt<128, 128, 64, true><<<g1, 256, 0, stream>>>(
                inseq + (size_t)c * CHUNK_T * BATCH * Kin, wih[L], b_ih[L], gx, Kin, GATES);
            for (int tt = 0; tt < CHUNK_T; ++tt) {
                int t = c * CHUNK_T + tt;
                k_step<<<256, 256, 0, stream>>>(gx, outseq, whhR[L], b_hh[L], hf, t, tt * BATCH);
            }
        }
        inseq = outseq;
        outseq = (outseq == hseqA) ? hseqB : hseqA;
    }

    k_bn_stats<<<HIDDEN / 256, 256, 0, stream>>>(hf, gamma, beta, abuf, bbuf);
    k_fc<<<BATCH, 64, 0, stream>>>(hf, abuf, bbuf, fcW, fcb, (float*)d_out);
}

// Round 4
// 3951.817 us; speedup vs baseline: 2.4691x; 1.1768x over previous
//
#include <hip/hip_runtime.h>
#include <hip/hip_bf16.h>
#include <stdint.h>

#define HIDDEN 1024
#define FEAT   64
#define BATCH  512
#define SEQ    64
#define GATES  3072        // 3*HIDDEN
#define CHUNK_T 16         // timesteps per gates_x chunk

typedef __attribute__((ext_vector_type(4))) float f32x4;
typedef __attribute__((ext_vector_type(8))) short s16x8;   // 8 bf16 = 4 VGPRs (MFMA A/B frag)

__device__ inline unsigned short f2bf(float f) {
    unsigned u = __builtin_bit_cast(unsigned, f);
    u += 0x7fff + ((u >> 16) & 1);          // round-to-nearest-even
    return (unsigned short)(u >> 16);
}
__device__ inline float bf2f(unsigned short s) {
    unsigned u = ((unsigned)s) << 16;
    return __builtin_bit_cast(float, u);
}

#define GLOAD_LDS16(g, l) __builtin_amdgcn_global_load_lds( \
    (const __attribute__((address_space(1))) unsigned int*)(g), \
    (__attribute__((address_space(3))) unsigned int*)(l), 16, 0, 0)

// ---------------- weight/input conversion ----------------
__global__ void k_convert(const float* __restrict__ src, unsigned short* __restrict__ dst, int n) {
    int i = blockIdx.x * blockDim.x + threadIdx.x;
    if (i < n) dst[i] = f2bf(src[i]);
}

// Whh (3*H, H) fp32 -> WhhR bf16, rows permuted so unit-tile ub's 48 rows
// {r:16, z:16, n:16} are contiguous: dst row d = ub*48 + g*16 + jj <- src row g*1024 + ub*16 + jj
__global__ void k_conv_whh(const float* __restrict__ src, unsigned short* __restrict__ dst) {
    int i = blockIdx.x * 256 + threadIdx.x;          // 3072*1024 threads
    int d = i >> 10, k = i & 1023;
    int ub = d / 48, rem = d - ub * 48;
    int g = rem >> 4, jj = rem & 15;
    int srow = g * 1024 + ub * 16 + jj;
    dst[i] = f2bf(src[(size_t)srow * 1024 + k]);
}

// x (B,T,F) fp32 -> xbf (T,B,F) bf16
__global__ void k_xpose(const float* __restrict__ x, unsigned short* __restrict__ xbf) {
    int i = blockIdx.x * blockDim.x + threadIdx.x;
    if (i >= BATCH * SEQ * FEAT) return;
    int f = i & 63, t = (i >> 6) & 63, b = i >> 12;
    xbf[((size_t)t * BATCH + b) * FEAT + f] = f2bf(x[i]);
}

// ---------------- BT-form MFMA GEMM for gates_x, XOR-swizzled LDS ----------------
// LDS content: LDS[bo] = global_tile[bo ^ ((row(bo)&7)<<4)], row = bo>>7 (128B rows).
template<int BM, int BN, int BK, bool STORE_BF16>
__global__ __launch_bounds__(256) void k_gemm_bt(
    const unsigned short* __restrict__ A,
    const unsigned short* __restrict__ B,
    const float* __restrict__ bias,
    void* __restrict__ C,
    int K, int ldc)
{
    __shared__ unsigned short As[BM * BK];
    __shared__ unsigned short Bs[BN * BK];
    const int tileN = blockIdx.x * BN;
    const int tileM = blockIdx.y * BM;
    const int wid  = threadIdx.x >> 6;
    const int lane = threadIdx.x & 63;
    constexpr int WM = BM / 2, WN = BN / 2;
    constexpr int FM = WM / 16, FN = WN / 16;
    const int wm0 = (wid >> 1) * WM;
    const int wn0 = (wid & 1) * WN;
    const int l15 = lane & 15, hi = lane >> 4;
    const int swz = (l15 & 7) << 4;

    f32x4 acc[FM][FN];
    const f32x4 zero = {0.f, 0.f, 0.f, 0.f};
#pragma unroll
    for (int i = 0; i < FM; ++i)
#pragma unroll
        for (int j = 0; j < FN; ++j) acc[i][j] = zero;

    constexpr int SPR = BK / 8;            // 16B segments per row (8 for BK=64)
    constexpr int RA = BM * SPR / 256;
    constexpr int RB = BN * SPR / 256;

    for (int k0 = 0; k0 < K; k0 += BK) {
        __syncthreads();
#pragma unroll
        for (int r = 0; r < RA; ++r) {
            int sbase = r * 256 + wid * 64;
            int s = sbase + lane;
            int row = s >> 3;
            int colb = ((s & 7) << 4) ^ ((row & 7) << 4);   // pre-swizzled source column
            const char* g = (const char*)A + ((size_t)(tileM + row) * K + k0) * 2 + colb;
            GLOAD_LDS16(g, As + sbase * 8);
        }
#pragma unroll
        for (int r = 0; r < RB; ++r) {
            int sbase = r * 256 + wid * 64;
            int s = sbase + lane;
            int row = s >> 3;
            int colb = ((s & 7) << 4) ^ ((row & 7) << 4);
            const char* g = (const char*)B + ((size_t)(tileN + row) * K + k0) * 2 + colb;
            GLOAD_LDS16(g, Bs + sbase * 8);
        }
        __syncthreads();

#pragma unroll
        for (int kk = 0; kk < BK / 32; ++kk) {
            s16x8 a[FM], b[FN];
#pragma unroll
            for (int i = 0; i < FM; ++i) {
                int bo = (wm0 + i * 16 + l15) * (BK * 2) + kk * 64 + (hi << 4);
                a[i] = *(const s16x8*)((const char*)As + (bo ^ swz));
            }
#pragma unroll
            for (int j = 0; j < FN; ++j) {
                int bo = (wn0 + j * 16 + l15) * (BK * 2) + kk * 64 + (hi << 4);
                b[j] = *(const s16x8*)((const char*)Bs + (bo ^ swz));
            }
#pragma unroll
            for (int i = 0; i < FM; ++i)
#pragma unroll
                for (int j = 0; j < FN; ++j)
                    acc[i][j] = __builtin_amdgcn_mfma_f32_16x16x32_bf16(a[i], b[j], acc[i][j], 0, 0, 0);
        }
    }

    const int r4 = (lane >> 4) * 4;
    const int cn = lane & 15;
#pragma unroll
    for (int i = 0; i < FM; ++i)
#pragma unroll
        for (int j = 0; j < FN; ++j)
#pragma unroll
            for (int r = 0; r < 4; ++r) {
                int row = tileM + wm0 + i * 16 + r4 + r;
                int col = tileN + wn0 + j * 16 + cn;
                float v = acc[i][j][r];
                if (bias) v += bias[col];
                if (STORE_BF16)
                    ((unsigned short*)C)[(size_t)row * ldc + col] = f2bf(v);
                else
                    ((float*)C)[(size_t)row * ldc + col] = v;
            }
}

// ---------------- fused per-timestep recurrent kernel, v2 ----------------
// grid 256 x 512 threads (8 waves). mb = bid&3, ub = bid>>2.
// Block: rows [mb*128,+128) x units [ub*16,+16), all 3 gates.
// 8 waves = 4 row-bands (32 rows) x 2 K-halves (split-K, LDS reduce).
// B = 48 permuted Whh rows in 96KB LDS (XOR-swizzled); A (h_{t-1} bf16) global->VGPR with
// rolling 4-deep prefetch. Carry is bf16 hseq (no fp32 hf). Gate math in epilogue (kh==0 waves).
__global__ __launch_bounds__(512) void k_step(
    const unsigned short* __restrict__ gx,     // (CHUNK_T*BATCH, 3072) bf16
    unsigned short* __restrict__ hseq,         // (SEQ, BATCH, HIDDEN) bf16: reads t-1, writes t
    const unsigned short* __restrict__ whhR,   // (3072, 1024) bf16 permuted
    const float* __restrict__ bhh,
    int t, int gxrow0)
{
    __shared__ unsigned short Bs[48 * 1024];   // 96 KB swizzled slab
    __shared__ f32x4 Sc[4 * 6 * 64];           // 24 KB split-K reduce scratch
    const int bid = blockIdx.x;
    const int mb = bid & 3;
    const int ub = bid >> 2;
    const int tid = threadIdx.x;
    const int wid = tid >> 6, lane = tid & 63;
    const int kh = wid & 1, band = wid >> 1;
    const int l15 = lane & 15, hi = lane >> 4;
    const int j = ub * 16 + l15;

    f32x4 acc[2][3];
    const f32x4 zero = {0.f, 0.f, 0.f, 0.f};
#pragma unroll
    for (int i = 0; i < 2; ++i)
#pragma unroll
        for (int g = 0; g < 3; ++g) acc[i][g] = zero;

    if (t > 0) {
        // ---- stage B slab: 96 x 1KB groups over 8 waves, pre-swizzled source ----
        {
            const char* slab = (const char*)whhR + (size_t)ub * 98304;
            char* lbase = (char*)Bs;
            int laneoff = lane << 4;
#pragma unroll
            for (int r = 0; r < 12; ++r) {
                int base = (wid * 12 + r) << 10;
                int s = ((base >> 11) & 7) << 4;        // row = base>>11 (2KB rows)
                GLOAD_LDS16(slab + base + (laneoff ^ s), lbase + base);
            }
        }
        // ---- A prefetch (global->VGPR, independent of LDS stage) ----
        const char* aBase = (const char*)(hseq + (size_t)(t - 1) * (BATCH * HIDDEN));
        const char* pa0 = aBase + (size_t)(mb * 128 + band * 32 + l15) * 2048 + (hi << 4) + kh * 1024;
        const char* pa1 = pa0 + 16 * 2048;
        s16x8 a0[4], a1[4];
#pragma unroll
        for (int p = 0; p < 4; ++p) {
            a0[p] = *(const s16x8*)(pa0 + p * 64);
            a1[p] = *(const s16x8*)(pa1 + p * 64);
        }
        __syncthreads();

        // ---- K-loop: this wave's 16 of 32 K-slices; B from swizzled LDS ----
        const char* lB = (const char*)Bs;
        const int swz = (l15 & 7) << 4;
        const int kb0 = kh * 1024 + (hi << 4);
        const int boff0 = (l15)      * 2048 + kb0;
        const int boff1 = (16 + l15) * 2048 + kb0;
        const int boff2 = (32 + l15) * 2048 + kb0;
#pragma unroll
        for (int ks = 0; ks < 16; ++ks) {
            s16x8 ca0 = a0[ks & 3], ca1 = a1[ks & 3];
            if (ks < 12) {
                a0[ks & 3] = *(const s16x8*)(pa0 + (ks + 4) * 64);
                a1[ks & 3] = *(const s16x8*)(pa1 + (ks + 4) * 64);
            }
            s16x8 b0 = *(const s16x8*)(lB + ((boff0 + ks * 64) ^ swz));
            s16x8 b1 = *(const s16x8*)(lB + ((boff1 + ks * 64) ^ swz));
            s16x8 b2 = *(const s16x8*)(lB + ((boff2 + ks * 64) ^ swz));
            acc[0][0] = __builtin_amdgcn_mfma_f32_16x16x32_bf16(ca0, b0, acc[0][0], 0, 0, 0);
            acc[0][1] = __builtin_amdgcn_mfma_f32_16x16x32_bf16(ca0, b1, acc[0][1], 0, 0, 0);
            acc[0][2] = __builtin_amdgcn_mfma_f32_16x16x32_bf16(ca0, b2, acc[0][2], 0, 0, 0);
            acc[1][0] = __builtin_amdgcn_mfma_f32_16x16x32_bf16(ca1, b0, acc[1][0], 0, 0, 0);
            acc[1][1] = __builtin_amdgcn_mfma_f32_16x16x32_bf16(ca1, b1, acc[1][1], 0, 0, 0);
            acc[1][2] = __builtin_amdgcn_mfma_f32_16x16x32_bf16(ca1, b2, acc[1][2], 0, 0, 0);
        }

        // ---- split-K reduction through LDS (conflict-free: lane*16B contiguous) ----
        if (kh == 1) {
#pragma unroll
            for (int q = 0; q < 6; ++q)
                Sc[(band * 6 + q) * 64 + lane] = acc[q / 3][q % 3];
        }
        __syncthreads();
        if (kh == 0) {
#pragma unroll
            for (int i = 0; i < 2; ++i)
#pragma unroll
                for (int g = 0; g < 3; ++g)
                    acc[i][g] += Sc[(band * 6 + (i * 3 + g)) * 64 + lane];
        }
    }

    // ---- fused gate epilogue (kh==0 waves: 4 waves cover the block's 128 rows) ----
    if (kh == 0) {
        const float bh_r = bhh[j], bh_z = bhh[HIDDEN + j], bh_n = bhh[2 * HIDDEN + j];
        const int erow0 = mb * 128 + band * 32 + hi * 4;
#pragma unroll
        for (int i = 0; i < 2; ++i)
#pragma unroll
            for (int r = 0; r < 4; ++r) {
                int brow = erow0 + i * 16 + r;
                size_t gxi = ((size_t)(gxrow0 + brow)) * GATES + j;
                float xr = bf2f(gx[gxi]);
                float xz = bf2f(gx[gxi + HIDDEN]);
                float xn = bf2f(gx[gxi + 2 * HIDDEN]);
                float rg = 1.f / (1.f + __expf(-(xr + acc[i][0][r] + bh_r)));
                float zg = 1.f / (1.f + __expf(-(xz + acc[i][1][r] + bh_z)));
                float ng = tanhf(xn + rg * (acc[i][2][r] + bh_n));
                size_t hidx = (size_t)brow * HIDDEN + j;
                float hv = (t > 0) ? bf2f(hseq[(size_t)(t - 1) * (BATCH * HIDDEN) + hidx]) : 0.f;
                float hnew = (1.f - zg) * ng + zg * hv;
                hseq[(size_t)t * (BATCH * HIDDEN) + hidx] = f2bf(hnew);
            }
    }
}

// ---------------- batch-norm over batch (bf16 input): fold to per-unit affine ----------------
__global__ void k_bn_stats(const unsigned short* __restrict__ h, const float* __restrict__ gamma,
                           const float* __restrict__ beta, float* __restrict__ a, float* __restrict__ bb)
{
    int j = blockIdx.x * 256 + threadIdx.x;
    float s = 0.f, q = 0.f;
    for (int b = 0; b < BATCH; ++b) {
        float v = bf2f(h[(size_t)b * HIDDEN + j]);
        s += v; q += v * v;
    }
    float mu = s * (1.f / BATCH);
    float var = q * (1.f / BATCH) - mu * mu;
    float rs = rsqrtf(var + 1e-5f);
    float aj = gamma[j] * rs;
    a[j] = aj;
    bb[j] = beta[j] - mu * aj;
}

// ---------------- FC(1024->1) + sigmoid ----------------
__global__ void k_fc(const unsigned short* __restrict__ h, const float* __restrict__ a, const float* __restrict__ bb,
                     const float* __restrict__ fcW, const float* __restrict__ fcb, float* __restrict__ out)
{
    int b = blockIdx.x;
    int lane = threadIdx.x;
    float s = 0.f;
    for (int j = lane; j < HIDDEN; j += 64)
        s += (bf2f(h[(size_t)b * HIDDEN + j]) * a[j] + bb[j]) * fcW[j];
#pragma unroll
    for (int m = 32; m; m >>= 1) s += __shfl_xor(s, m, 64);
    if (lane == 0) out[b] = 1.f / (1.f + __expf(-(s + fcb[0])));
}

// ---------------- driver ----------------
extern "C" void kernel_launch(void* const* d_in, const int* in_sizes, int n_in,
                              void* d_out, int out_size, void* d_ws, size_t ws_size,
                              hipStream_t stream)
{
    const float* x = (const float*)d_in[0];
    const float* W_ih[3] = {(const float*)d_in[1], (const float*)d_in[5], (const float*)d_in[9]};
    const float* W_hh[3] = {(const float*)d_in[2], (const float*)d_in[6], (const float*)d_in[10]};
    const float* b_ih[3] = {(const float*)d_in[3], (const float*)d_in[7], (const float*)d_in[11]};
    const float* b_hh[3] = {(const float*)d_in[4], (const float*)d_in[8], (const float*)d_in[12]};
    const float* gamma = (const float*)d_in[13];
    const float* beta  = (const float*)d_in[14];
    const float* fcW   = (const float*)d_in[15];
    const float* fcb   = (const float*)d_in[16];

    char* ws = (char*)d_ws;
    size_t off = 0;
    auto alloc = [&](size_t bytes) -> void* {
        void* p = ws + off;
        off = (off + bytes + 255) & ~(size_t)255;
        return p;
    };
    unsigned short* wih[3]; unsigned short* whhR[3];
    wih[0]  = (unsigned short*)alloc((size_t)GATES * FEAT * 2);
    whhR[0] = (unsigned short*)alloc((size_t)GATES * HIDDEN * 2);
    wih[1]  = (unsigned short*)alloc((size_t)GATES * HIDDEN * 2);
    whhR[1] = (unsigned short*)alloc((size_t)GATES * HIDDEN * 2);
    wih[2]  = (unsigned short*)alloc((size_t)GATES * HIDDEN * 2);
    whhR[2] = (unsigned short*)alloc((size_t)GATES * HIDDEN * 2);
    unsigned short* xbf   = (unsigned short*)alloc((size_t)SEQ * BATCH * FEAT * 2);
    unsigned short* hseqA = (unsigned short*)alloc((size_t)SEQ * BATCH * HIDDEN * 2);
    unsigned short* hseqB = (unsigned short*)alloc((size_t)SEQ * BATCH * HIDDEN * 2);
    unsigned short* gx    = (unsigned short*)alloc((size_t)CHUNK_T * BATCH * GATES * 2);
    float* abuf = (float*)alloc(HIDDEN * 4);
    float* bbuf = (float*)alloc(HIDDEN * 4);

    // weights -> bf16 (stateless every call)
    k_convert<<<(GATES * FEAT + 255) / 256, 256, 0, stream>>>(W_ih[0], wih[0], GATES * FEAT);
    for (int L = 0; L < 3; ++L) {
        k_conv_whh<<<(GATES * HIDDEN) / 256, 256, 0, stream>>>(W_hh[L], whhR[L]);
        if (L) k_convert<<<(GATES * HIDDEN + 255) / 256, 256, 0, stream>>>(W_ih[L], wih[L], GATES * HIDDEN);
    }
    k_xpose<<<(BATCH * SEQ * FEAT + 255) / 256, 256, 0, stream>>>(x, xbf);

    const unsigned short* inseq = xbf;
    unsigned short* outseq = hseqA;
    for (int L = 0; L < 3; ++L) {
        int Kin = (L == 0) ? FEAT : HIDDEN;
        for (int c = 0; c < SEQ / CHUNK_T; ++c) {
            dim3 g1(GATES / 128, (CHUNK_T * BATCH) / 128);
            k_gemm_bt<128, 128, 64, true><<<g1, 256, 0, stream>>>(
                inseq + (size_t)c * CHUNK_T * BATCH * Kin, wih[L], b_ih[L], gx, Kin, GATES);
            for (int tt = 0; tt < CHUNK_T; ++tt) {
                int t = c * CHUNK_T + tt;
                k_step<<<256, 512, 0, stream>>>(gx, outseq, whhR[L], b_hh[L], t, tt * BATCH);
            }
        }
        inseq = outseq;
        outseq = (outseq == hseqA) ? hseqB : hseqA;
    }

    const unsigned short* hlast = inseq + (size_t)(SEQ - 1) * (BATCH * HIDDEN);
    k_bn_stats<<<HIDDEN / 256, 256, 0, stream>>>(hlast, gamma, beta, abuf, bbuf);
    k_fc<<<BATCH, 64, 0, stream>>>(hlast, abuf, bbuf, fcW, fcb, (float*)d_out);
}